// Round 2
// baseline (724.404 us; speedup 1.0000x reference)
//
#include <hip/hip_runtime.h>
#include <math.h>

#define DIM   4096
#define NITER 20
#define EPSF  1e-10f
#define NB    256
#define NT    1024
#define RPB   16           // rows per block
#define NRG   16           // fallback path

typedef __attribute__((ext_vector_type(4))) unsigned short ushort4_t;
typedef unsigned long long u64;

// ---------- bf16 <-> f32 (range to 2^127 covers E=exp(la) spread) ----------
__device__ __forceinline__ float bf2f(unsigned short b) {
    unsigned int x = ((unsigned int)b) << 16;
    return __builtin_bit_cast(float, x);
}
__device__ __forceinline__ unsigned short f2bf(float f) {
    unsigned int x = __builtin_bit_cast(unsigned int, f);
    x += 0x7fffu + ((x >> 16) & 1u);          // round-to-nearest-even
    return (unsigned short)(x >> 16);
}

// ---------- tagged 64-bit dataflow atoms: (tag<<32 | f32 bits) ----------
// One relaxed agent-scope atomic carries payload + readiness flag together:
// consumer poll IS the data read. No barriers, no fences, no store ordering.
__device__ __forceinline__ u64 ld64(const u64* p) {
    return __hip_atomic_load(p, __ATOMIC_RELAXED, __HIP_MEMORY_SCOPE_AGENT);
}
__device__ __forceinline__ void st_tag(u64* p, float v, unsigned tag) {
    u64 w = ((u64)tag << 32) | (u64)__builtin_bit_cast(unsigned int, v);
    __hip_atomic_store(p, w, __ATOMIC_RELAXED, __HIP_MEMORY_SCOPE_AGENT);
}
__device__ __forceinline__ unsigned tag_of(u64 v) { return (unsigned)(v >> 32); }
__device__ __forceinline__ float    val_of(u64 v) {
    return __builtin_bit_cast(float, (unsigned int)(v & 0xffffffffull));
}

// zero the tagged scratch (part: NB*DIM words in out; cg: DIM words in ws)
__global__ __launch_bounds__(256) void zero_scratch(u64* part, u64* cgt) {
    const size_t n = (size_t)NB * DIM;
    size_t idx = (size_t)blockIdx.x * blockDim.x + threadIdx.x;
    size_t stride = (size_t)gridDim.x * blockDim.x;
    for (size_t i = idx; i < n; i += stride) part[i] = 0ull;
    if (idx < DIM) cgt[idx] = 0ull;
}

// ============ persistent multiplicative Sinkhorn, barrier-free dataflow ==========
// Row step:  u_i = 1 / sum_j E_ij * w_j               (block-local, wave<->row)
// Col step:  part[b][j] = sum_{i in blk} E_ij*u_i     (tagged it+1)
//            combine: block b reduces part[0..255][16b..16b+15] -> w, tagged it+1
//            refresh: every block polls all 4096 tagged w words
// Safety: a block can only overwrite part/cg with tag it+2 after its refresh(it),
// which transitively requires every block to have consumed tag it+1. Final-phase
// overwrite of part (in `out`) is safe for the same reason.
__global__ __launch_bounds__(NT, 4) void sinkhorn_flow(
        const float* __restrict__ logits, const float* __restrict__ noise,
        float* __restrict__ out, u64* __restrict__ cgt, u64* __restrict__ part) {
    __shared__ unsigned short lm[RPB][DIM];  // 128 KiB: block's 16 rows of E (bf16)
    __shared__ float          lw[DIM];       //  16 KiB: local copy of w
    __shared__ float          ru[RPB];       // row reciprocals u_i
    __shared__ float4         red[16][4];    //   1 KiB: combine cross-wave stage

    const int t = threadIdx.x;
    const int b = blockIdx.x;
    const int wave = t >> 6, lane = t & 63;
    const int g0 = b * RPB;

    // ---- init: E = exp(logits) / (eps - log(noise+eps)) -> bf16 in LDS ----
#pragma unroll
    for (int r = 0; r < RPB; ++r) {
        const float4 l = *(const float4*)(logits + (size_t)(g0 + r) * DIM + 4 * t);
        const float4 u = *(const float4*)(noise  + (size_t)(g0 + r) * DIM + 4 * t);
        ushort4_t e;
        e.x = f2bf(__expf(l.x) * __builtin_amdgcn_rcpf(EPSF - __logf(u.x + EPSF)));
        e.y = f2bf(__expf(l.y) * __builtin_amdgcn_rcpf(EPSF - __logf(u.y + EPSF)));
        e.z = f2bf(__expf(l.z) * __builtin_amdgcn_rcpf(EPSF - __logf(u.z + EPSF)));
        e.w = f2bf(__expf(l.w) * __builtin_amdgcn_rcpf(EPSF - __logf(u.w + EPSF)));
        *(ushort4_t*)&lm[r][4 * t] = e;
    }
    *(float4*)&lw[4 * t] = make_float4(1.f, 1.f, 1.f, 1.f);
    __syncthreads();

    for (int it = 0; it < NITER; ++it) {
        const unsigned tg = (unsigned)(it + 1);

        // ---------- row sums: wave w <-> row w, FMA pass, shfl butterfly ----
        {
            float4 s4 = make_float4(0.f, 0.f, 0.f, 0.f);
#pragma unroll
            for (int k = 0; k < 16; ++k) {
                const int col = (k * 64 + lane) * 4;
                const ushort4_t e  = *(const ushort4_t*)&lm[wave][col];
                const float4    w4 = *(const float4*)&lw[col];
                s4.x += bf2f(e.x) * w4.x;
                s4.y += bf2f(e.y) * w4.y;
                s4.z += bf2f(e.z) * w4.z;
                s4.w += bf2f(e.w) * w4.w;
            }
            float s = (s4.x + s4.y) + (s4.z + s4.w);
#pragma unroll
            for (int o = 1; o < 64; o <<= 1) s += __shfl_xor(s, o, 64);
            if (lane == 0) ru[wave] = __builtin_amdgcn_rcpf(s);
        }
        __syncthreads();

        // ---------- col partials -> tagged publish (store IS the sync) ----
        {
            float4 p = make_float4(0.f, 0.f, 0.f, 0.f);
#pragma unroll
            for (int r2 = 0; r2 < RPB; ++r2) {
                const ushort4_t e = *(const ushort4_t*)&lm[r2][4 * t];
                const float uu = ru[r2];
                p.x += bf2f(e.x) * uu;
                p.y += bf2f(e.y) * uu;
                p.z += bf2f(e.z) * uu;
                p.w += bf2f(e.w) * uu;
            }
            u64* pp = part + (size_t)b * DIM + 4 * t;
            st_tag(pp + 0, p.x, tg);
            st_tag(pp + 1, p.y, tg);
            st_tag(pp + 2, p.z, tg);
            st_tag(pp + 3, p.w, tg);
        }

        // ---------- combine: block b reduces cols 16b..16b+15 over 256 rows ----
        // thread t: row r=t>>2, group g=t&3 -> one 64B line per row, coalesced
        {
            const int r = t >> 2, g = t & 3;
            const u64* q = part + (size_t)r * DIM + 16 * b + 4 * g;
            u64 v0, v1, v2, v3;
            for (;;) {
                v0 = ld64(q + 0); v1 = ld64(q + 1); v2 = ld64(q + 2); v3 = ld64(q + 3);
                if (tag_of(v0) >= tg && tag_of(v1) >= tg &&
                    tag_of(v2) >= tg && tag_of(v3) >= tg) break;
                __builtin_amdgcn_s_sleep(1);
            }
            float4 s4 = make_float4(val_of(v0), val_of(v1), val_of(v2), val_of(v3));
#pragma unroll
            for (int o = 4; o < 64; o <<= 1) {   // reduce over 16 rows within wave
                s4.x += __shfl_xor(s4.x, o, 64);
                s4.y += __shfl_xor(s4.y, o, 64);
                s4.z += __shfl_xor(s4.z, o, 64);
                s4.w += __shfl_xor(s4.w, o, 64);
            }
            if (lane < 4) red[wave][lane] = s4;
        }
        __syncthreads();
        if (t < 64) {                            // wave 0: reduce across 16 waves
            float4 s4 = red[t >> 2][t & 3];
#pragma unroll
            for (int o = 4; o < 64; o <<= 1) {
                s4.x += __shfl_xor(s4.x, o, 64);
                s4.y += __shfl_xor(s4.y, o, 64);
                s4.z += __shfl_xor(s4.z, o, 64);
                s4.w += __shfl_xor(s4.w, o, 64);
            }
            if (t < 4) {                         // publish w = 1/colsum, tagged
                u64* cq = cgt + 16 * b + 4 * t;
                st_tag(cq + 0, __builtin_amdgcn_rcpf(s4.x), tg);
                st_tag(cq + 1, __builtin_amdgcn_rcpf(s4.y), tg);
                st_tag(cq + 2, __builtin_amdgcn_rcpf(s4.z), tg);
                st_tag(cq + 3, __builtin_amdgcn_rcpf(s4.w), tg);
            }
        }

        // ---------- refresh: poll all tagged w words this thread consumes ----
        {
            const u64* cq = cgt + 4 * t;
            u64 v0, v1, v2, v3;
            for (;;) {
                v0 = ld64(cq + 0); v1 = ld64(cq + 1); v2 = ld64(cq + 2); v3 = ld64(cq + 3);
                if (tag_of(v0) >= tg && tag_of(v1) >= tg &&
                    tag_of(v2) >= tg && tag_of(v3) >= tg) break;
                __builtin_amdgcn_s_sleep(1);
            }
            lw[4 * t + 0] = val_of(v0);
            lw[4 * t + 1] = val_of(v1);
            lw[4 * t + 2] = val_of(v2);
            lw[4 * t + 3] = val_of(v3);
        }
        __syncthreads();
    }

    // ---------- final: out = E * u_i * w_j ----------
    const float4 w4 = *(const float4*)&lw[4 * t];
#pragma unroll
    for (int r = 0; r < RPB; ++r) {
        const ushort4_t e = *(const ushort4_t*)&lm[r][4 * t];
        const float uu = ru[r];
        float4 o;
        o.x = bf2f(e.x) * (uu * w4.x);
        o.y = bf2f(e.y) * (uu * w4.y);
        o.z = bf2f(e.z) * (uu * w4.z);
        o.w = bf2f(e.w) * (uu * w4.w);
        *(float4*)(out + (size_t)(g0 + r) * DIM + 4 * t) = o;
    }
}

// =================== fallback pipeline (round-1, known-good 769 us) ==============
__device__ __forceinline__ float waveMaxF(float v) {
#pragma unroll
    for (int o = 32; o > 0; o >>= 1) v = fmaxf(v, __shfl_down(v, o, 64));
    return v;
}
__device__ __forceinline__ float waveSumF(float v) {
#pragma unroll
    for (int o = 32; o > 0; o >>= 1) v += __shfl_down(v, o, 64);
    return v;
}

__global__ __launch_bounds__(256) void init_k(const float* __restrict__ logits,
                                              const float* __restrict__ noise,
                                              float* __restrict__ L0,
                                              float* __restrict__ c) {
    int idx = blockIdx.x * blockDim.x + threadIdx.x;
    int stride = gridDim.x * blockDim.x;
    const float4* l4 = (const float4*)logits;
    const float4* n4 = (const float4*)noise;
    float4* o4 = (float4*)L0;
    for (int p = idx; p < DIM * DIM / 4; p += stride) {
        float4 l = l4[p];
        float4 u = n4[p];
        float4 o;
        o.x = l.x - __logf(-__logf(u.x + EPSF) + EPSF);
        o.y = l.y - __logf(-__logf(u.y + EPSF) + EPSF);
        o.z = l.z - __logf(-__logf(u.z + EPSF) + EPSF);
        o.w = l.w - __logf(-__logf(u.w + EPSF) + EPSF);
        o4[p] = o;
    }
    if (idx < DIM) c[idx] = 0.0f;
}

__global__ __launch_bounds__(256) void row_lse(const float* __restrict__ L0,
                                               const float* __restrict__ c,
                                               float* __restrict__ r) {
    __shared__ float red[8];
    const int row = blockIdx.x;
    const int t = threadIdx.x;
    const float4* a4 = (const float4*)(L0 + (size_t)row * DIM);
    const float4* c4 = (const float4*)c;
    float v[16];
    float m = -INFINITY;
#pragma unroll
    for (int k = 0; k < 4; ++k) {
        float4 a  = a4[t + k * 256];
        float4 cc = c4[t + k * 256];
        v[4 * k + 0] = a.x - cc.x;
        v[4 * k + 1] = a.y - cc.y;
        v[4 * k + 2] = a.z - cc.z;
        v[4 * k + 3] = a.w - cc.w;
        m = fmaxf(m, fmaxf(fmaxf(v[4 * k], v[4 * k + 1]), fmaxf(v[4 * k + 2], v[4 * k + 3])));
    }
    m = waveMaxF(m);
    const int lane = t & 63, wid = t >> 6;
    if (lane == 0) red[wid] = m;
    __syncthreads();
    const float bm = fmaxf(fmaxf(red[0], red[1]), fmaxf(red[2], red[3]));
    float s = 0.0f;
#pragma unroll
    for (int q = 0; q < 16; ++q) s += __expf(v[q] - bm);
    s = waveSumF(s);
    if (lane == 0) red[4 + wid] = s;
    __syncthreads();
    if (t == 0) r[row] = bm + __logf(red[4] + red[5] + red[6] + red[7]);
}

__global__ __launch_bounds__(1024) void col_partial(const float* __restrict__ L0,
                                                    const float* __restrict__ r,
                                                    float2* __restrict__ part) {
    __shared__ float sr[256];
    __shared__ float smm[1024];
    __shared__ float sms[1024];
    const int g = blockIdx.x, h = blockIdx.y;
    const int tc = threadIdx.x & 255;
    const int ln = threadIdx.x >> 8;
    if (threadIdx.x < 256) sr[threadIdx.x] = r[h * 256 + threadIdx.x];
    __syncthreads();
    const int j = g * 256 + tc;
    float m = -INFINITY, s = 0.0f;
#pragma unroll 4
    for (int k = 0; k < 64; ++k) {
        int ii = k * 4 + ln;
        float v = L0[(size_t)(h * 256 + ii) * DIM + j] - sr[ii];
        float nm = fmaxf(m, v);
        s = s * __expf(m - nm) + __expf(v - nm);
        m = nm;
    }
    smm[threadIdx.x] = m;
    sms[threadIdx.x] = s;
    __syncthreads();
    if (threadIdx.x < 256) {
        float m0 = smm[tc], m1 = smm[tc + 256], m2 = smm[tc + 512], m3 = smm[tc + 768];
        float M = fmaxf(fmaxf(m0, m1), fmaxf(m2, m3));
        float S = sms[tc] * __expf(m0 - M) + sms[tc + 256] * __expf(m1 - M) +
                  sms[tc + 512] * __expf(m2 - M) + sms[tc + 768] * __expf(m3 - M);
        part[h * DIM + j] = make_float2(M, S);
    }
}

__global__ __launch_bounds__(256) void col_combine(const float2* __restrict__ part,
                                                   float* __restrict__ c) {
    int j = blockIdx.x * 256 + threadIdx.x;
    float pm[NRG], ps[NRG];
    float M = -INFINITY;
#pragma unroll
    for (int h = 0; h < NRG; ++h) {
        float2 p = part[h * DIM + j];
        pm[h] = p.x; ps[h] = p.y;
        M = fmaxf(M, p.x);
    }
    float S = 0.0f;
#pragma unroll
    for (int h = 0; h < NRG; ++h) S += ps[h] * __expf(pm[h] - M);
    c[j] = M + __logf(S);
}

__global__ __launch_bounds__(256) void final_exp(float* __restrict__ L0,
                                                 const float* __restrict__ r,
                                                 const float* __restrict__ c) {
    const float4* c4 = (const float4*)c;
    float4* a4 = (float4*)L0;
    int idx = blockIdx.x * blockDim.x + threadIdx.x;
    int stride = gridDim.x * blockDim.x;
    for (int p = idx; p < DIM * DIM / 4; p += stride) {
        int i  = p >> 10;
        int j4 = p & 1023;
        float4 a = a4[p];
        float rrv = r[i];
        float4 ccv = c4[j4];
        a.x = __expf(a.x - rrv - ccv.x);
        a.y = __expf(a.y - rrv - ccv.y);
        a.z = __expf(a.z - rrv - ccv.z);
        a.w = __expf(a.w - rrv - ccv.w);
        a4[p] = a;
    }
}

// ====================================== launch ===================================
extern "C" void kernel_launch(void* const* d_in, const int* in_sizes, int n_in,
                              void* d_out, int out_size, void* d_ws, size_t ws_size,
                              hipStream_t stream) {
    const float* logits = (const float*)d_in[0];
    const float* noise  = (const float*)d_in[1];
    float* out = (float*)d_out;

    bool tried_flow = false;
    if (ws_size >= 32768) {
        u64* cgt  = (u64*)d_ws;           // 32 KiB tagged w vector
        u64* part = (u64*)d_out;          // first 8 MiB of out = tagged partials
        zero_scratch<<<2048, 256, 0, stream>>>(part, cgt);
        void* args[] = { (void*)&logits, (void*)&noise, (void*)&out,
                         (void*)&cgt, (void*)&part };
        hipError_t err = hipLaunchCooperativeKernel((const void*)sinkhorn_flow,
                                                    dim3(NB), dim3(NT), args, 0, stream);
        tried_flow = (err == hipSuccess);
    }
    if (!tried_flow) {
        // fallback: round-1 multi-kernel pipeline (known-good)
        float* ws = (float*)d_ws;
        float*  r    = ws;
        float*  cf   = ws + DIM;
        float2* part = (float2*)(ws + 2 * DIM);
        init_k<<<4096, 256, 0, stream>>>(logits, noise, out, cf);
        for (int t = 0; t < NITER; ++t) {
            row_lse<<<DIM, 256, 0, stream>>>(out, cf, r);
            col_partial<<<dim3(16, 16), 1024, 0, stream>>>(out, r, part);
            col_combine<<<16, 256, 0, stream>>>(part, cf);
        }
        final_exp<<<4096, 256, 0, stream>>>(out, r, cf);
    }
}

// Round 3
// 507.497 us; speedup vs baseline: 1.4274x; 1.4274x over previous
//
#include <hip/hip_runtime.h>
#include <math.h>

#define DIM   4096
#define NITER 20
#define EPSF  1e-10f
#define NB    256
#define NT    1024
#define RPB   16           // rows per block
#define NRG   16           // fallback path

typedef __attribute__((ext_vector_type(4))) unsigned short ushort4_t;
typedef __attribute__((ext_vector_type(2))) unsigned short ushort2_t;
typedef unsigned long long u64;

// ---------- bf16 <-> f32 (range to 2^127 covers E=exp(la) spread) ----------
__device__ __forceinline__ float bf2f(unsigned short b) {
    unsigned int x = ((unsigned int)b) << 16;
    return __builtin_bit_cast(float, x);
}
__device__ __forceinline__ unsigned short f2bf(float f) {
    unsigned int x = __builtin_bit_cast(unsigned int, f);
    x += 0x7fffu + ((x >> 16) & 1u);          // round-to-nearest-even
    return (unsigned short)(x >> 16);
}

// ---------- MALL-coherent access (agent scope bypasses non-coherent L2) ----------
__device__ __forceinline__ u64 ld64(const u64* p) {
    return __hip_atomic_load(p, __ATOMIC_RELAXED, __HIP_MEMORY_SCOPE_AGENT);
}
__device__ __forceinline__ unsigned ld32(const unsigned* p) {
    return __hip_atomic_load(p, __ATOMIC_RELAXED, __HIP_MEMORY_SCOPE_AGENT);
}
__device__ __forceinline__ void st32(unsigned* p, unsigned v) {
    __hip_atomic_store(p, v, __ATOMIC_RELAXED, __HIP_MEMORY_SCOPE_AGENT);
}
// dense 64-bit payload store: (b<<32)|a of two f32 — one wave-contiguous dwordx2
__device__ __forceinline__ void st_co2(float* p, float a, float b) {
    u64 v = ((u64)__builtin_bit_cast(unsigned int, b) << 32) |
            (u64)__builtin_bit_cast(unsigned int, a);
    __hip_atomic_store((u64*)p, v, __ATOMIC_RELAXED, __HIP_MEMORY_SCOPE_AGENT);
}
__device__ __forceinline__ float lo_f(u64 v) {
    return __builtin_bit_cast(float, (unsigned int)(v & 0xffffffffull));
}
__device__ __forceinline__ float hi_f(u64 v) {
    return __builtin_bit_cast(float, (unsigned int)(v >> 32));
}
// tagged atom for the tiny w-vector only: (tag<<32 | f32)
__device__ __forceinline__ void st_tag(u64* p, float v, unsigned tag) {
    u64 w = ((u64)tag << 32) | (u64)__builtin_bit_cast(unsigned int, v);
    __hip_atomic_store(p, w, __ATOMIC_RELAXED, __HIP_MEMORY_SCOPE_AGENT);
}
__device__ __forceinline__ unsigned tag_of(u64 v) { return (unsigned)(v >> 32); }

// zero tagged w vector (4096 u64) + barrier slots (256 u32)
__global__ __launch_bounds__(256) void zero_scratch(u64* cgt, unsigned* slots) {
    int idx = blockIdx.x * 256 + threadIdx.x;
    if (idx < DIM) cgt[idx] = 0ull;
    if (idx < NB) slots[idx] = 0u;
}

// ============ persistent multiplicative Sinkhorn, 1 barrier + tagged-w =========
// Row step:  u_i = 1 / sum_j E_ij * w_j               (block-local, wave<->row)
// Col step:  part[b][j] = sum_{i in blk} E_ij*u_i     (plain f32, dense stores)
//            slot-barrier A  (partials(it) all published)
//            combine: block b coalesced-reduces part[0..255][16b..16b+15],
//                     publishes w = 1/colsum as tagged u64 (tag=it+1)
//            refresh: thread t polls only its own 4 tagged words (no barrier B)
// ABA safety: cg overwrite with tag it+2 happens in combine(it+1), which is
// gated by barrier A(it+1), which requires every block's refresh(it). Partials
// overwrite (it+1) requires refresh(it) -> all combine(it) reads done. Final
// out stores overwriting the partial scratch region: same argument.
__global__ __launch_bounds__(NT, 4) void sinkhorn_flow(
        const float* __restrict__ logits, const float* __restrict__ noise,
        float* __restrict__ out, u64* __restrict__ cgt,
        unsigned* __restrict__ slots, float* __restrict__ part) {
    __shared__ unsigned short lm[RPB][DIM];  // 128 KiB: block's 16 rows of E (bf16)
    __shared__ float          lw[DIM];       //  16 KiB: local copy of w
    __shared__ float          ru[RPB];       // row reciprocals u_i
    __shared__ float4         red[16][4];    //   1 KiB: combine cross-wave stage

    const int t = threadIdx.x;
    const int b = blockIdx.x;
    const int wave = t >> 6, lane = t & 63;
    const int g0 = b * RPB;

    // ---- init: E = exp(logits) / (eps - log(noise+eps)) -> bf16 in LDS ----
#pragma unroll
    for (int r = 0; r < RPB; ++r) {
        const float4 l = *(const float4*)(logits + (size_t)(g0 + r) * DIM + 4 * t);
        const float4 u = *(const float4*)(noise  + (size_t)(g0 + r) * DIM + 4 * t);
        ushort4_t e;
        e.x = f2bf(__expf(l.x) * __builtin_amdgcn_rcpf(EPSF - __logf(u.x + EPSF)));
        e.y = f2bf(__expf(l.y) * __builtin_amdgcn_rcpf(EPSF - __logf(u.y + EPSF)));
        e.z = f2bf(__expf(l.z) * __builtin_amdgcn_rcpf(EPSF - __logf(u.z + EPSF)));
        e.w = f2bf(__expf(l.w) * __builtin_amdgcn_rcpf(EPSF - __logf(u.w + EPSF)));
        *(ushort4_t*)&lm[r][4 * t] = e;
    }
    *(float4*)&lw[4 * t] = make_float4(1.f, 1.f, 1.f, 1.f);
    __syncthreads();

    for (int it = 0; it < NITER; ++it) {
        const unsigned tg = (unsigned)(it + 1);

        // ---------- row sums: wave w <-> row w, FMA pass, shfl butterfly ----
        {
            float4 s4 = make_float4(0.f, 0.f, 0.f, 0.f);
#pragma unroll
            for (int k = 0; k < 16; ++k) {
                const int col = (k * 64 + lane) * 4;
                const ushort4_t e  = *(const ushort4_t*)&lm[wave][col];
                const float4    w4 = *(const float4*)&lw[col];
                s4.x += bf2f(e.x) * w4.x;
                s4.y += bf2f(e.y) * w4.y;
                s4.z += bf2f(e.z) * w4.z;
                s4.w += bf2f(e.w) * w4.w;
            }
            float s = (s4.x + s4.y) + (s4.z + s4.w);
#pragma unroll
            for (int o = 1; o < 64; o <<= 1) s += __shfl_xor(s, o, 64);
            if (lane == 0) ru[wave] = __builtin_amdgcn_rcpf(s);
        }
        __syncthreads();

        // ---------- col partials: thread t -> cols {2t,2t+1},{2048+2t,+1} ----
        // each st_co2 instruction is 64 lanes x 8 B contiguous (full lines)
        {
            float p00 = 0.f, p01 = 0.f, p10 = 0.f, p11 = 0.f;
#pragma unroll
            for (int r2 = 0; r2 < RPB; ++r2) {
                const ushort2_t e0 = *(const ushort2_t*)&lm[r2][2 * t];
                const ushort2_t e1 = *(const ushort2_t*)&lm[r2][2048 + 2 * t];
                const float uu = ru[r2];
                p00 += bf2f(e0.x) * uu;
                p01 += bf2f(e0.y) * uu;
                p10 += bf2f(e1.x) * uu;
                p11 += bf2f(e1.y) * uu;
            }
            float* pp = part + (size_t)b * DIM;
            st_co2(pp + 2 * t, p00, p01);
            st_co2(pp + 2048 + 2 * t, p10, p11);
        }

        // ---------- slot-store barrier A (partials ready) ----------
        __syncthreads();   // per-thread vmcnt drain: all partial stores MALL-acked
        if (t == 0) st32(slots + b, tg);
        if (wave == 0) {   // lane L polls slots[4L..4L+3] (4 coalesced lines)
            const unsigned* sp = slots + 4 * lane;
            for (;;) {
                unsigned s0 = ld32(sp + 0), s1 = ld32(sp + 1);
                unsigned s2 = ld32(sp + 2), s3 = ld32(sp + 3);
                bool ok = (s0 >= tg) & (s1 >= tg) & (s2 >= tg) & (s3 >= tg);
                if (__all(ok)) break;
                __builtin_amdgcn_s_sleep(1);
            }
        }
        __syncthreads();

        // ---------- combine: coalesced reduce of part[0..255][16b..16b+15] ----
        // thread t: row r=t>>2, group g=t&3 -> 16 B dense (4 threads per line)
        {
            const int r = t >> 2, g = t & 3;
            const u64* q = (const u64*)part + (size_t)r * (DIM / 2) + 8 * b + 2 * g;
            const u64 a0 = ld64(q + 0);
            const u64 a1 = ld64(q + 1);
            float4 s4 = make_float4(lo_f(a0), hi_f(a0), lo_f(a1), hi_f(a1));
#pragma unroll
            for (int o = 4; o < 64; o <<= 1) {   // sum the wave's 16 rows
                s4.x += __shfl_xor(s4.x, o, 64);
                s4.y += __shfl_xor(s4.y, o, 64);
                s4.z += __shfl_xor(s4.z, o, 64);
                s4.w += __shfl_xor(s4.w, o, 64);
            }
            if (lane < 4) red[wave][lane] = s4;
        }
        __syncthreads();
        if (t < 64) {                            // wave 0: reduce across 16 waves
            float4 s4 = red[t >> 2][t & 3];
#pragma unroll
            for (int o = 4; o < 64; o <<= 1) {
                s4.x += __shfl_xor(s4.x, o, 64);
                s4.y += __shfl_xor(s4.y, o, 64);
                s4.z += __shfl_xor(s4.z, o, 64);
                s4.w += __shfl_xor(s4.w, o, 64);
            }
            if (t < 4) {                         // publish w = 1/colsum, tagged
                float w0 = __builtin_amdgcn_rcpf(s4.x);
                float w1 = __builtin_amdgcn_rcpf(s4.y);
                float w2 = __builtin_amdgcn_rcpf(s4.z);
                float w3 = __builtin_amdgcn_rcpf(s4.w);
                u64* cq = cgt + 16 * b + 4 * t;
                st_tag(cq + 0, w0, tg);
                st_tag(cq + 1, w1, tg);
                st_tag(cq + 2, w2, tg);
                st_tag(cq + 3, w3, tg);
                // self-block shortcut: own columns land in LDS directly
                const int j0 = 16 * b + 4 * t;
                lw[j0 + 0] = w0; lw[j0 + 1] = w1; lw[j0 + 2] = w2; lw[j0 + 3] = w3;
            }
        }

        // ---------- refresh: thread t polls only ITS 4 tagged words ----------
        if ((t >> 2) != b) {       // own columns already in lw via shortcut
            const u64* cq = cgt + 4 * t;
            u64 v0, v1, v2, v3;
            for (;;) {
                v0 = ld64(cq + 0); v1 = ld64(cq + 1);
                v2 = ld64(cq + 2); v3 = ld64(cq + 3);
                if (tag_of(v0) >= tg && tag_of(v1) >= tg &&
                    tag_of(v2) >= tg && tag_of(v3) >= tg) break;
                __builtin_amdgcn_s_sleep(1);
            }
            lw[4 * t + 0] = lo_f(v0);
            lw[4 * t + 1] = lo_f(v1);
            lw[4 * t + 2] = lo_f(v2);
            lw[4 * t + 3] = lo_f(v3);
        }
        __syncthreads();
    }

    // ---------- final: out = E * u_i * w_j ----------
    const float4 w4 = *(const float4*)&lw[4 * t];
#pragma unroll
    for (int r = 0; r < RPB; ++r) {
        const ushort4_t e = *(const ushort4_t*)&lm[r][4 * t];
        const float uu = ru[r];
        float4 o;
        o.x = bf2f(e.x) * (uu * w4.x);
        o.y = bf2f(e.y) * (uu * w4.y);
        o.z = bf2f(e.z) * (uu * w4.z);
        o.w = bf2f(e.w) * (uu * w4.w);
        *(float4*)(out + (size_t)(g0 + r) * DIM + 4 * t) = o;
    }
}

// =================== fallback pipeline (round-1, known-good 769 us) ==============
__device__ __forceinline__ float waveMaxF(float v) {
#pragma unroll
    for (int o = 32; o > 0; o >>= 1) v = fmaxf(v, __shfl_down(v, o, 64));
    return v;
}
__device__ __forceinline__ float waveSumF(float v) {
#pragma unroll
    for (int o = 32; o > 0; o >>= 1) v += __shfl_down(v, o, 64);
    return v;
}

__global__ __launch_bounds__(256) void init_k(const float* __restrict__ logits,
                                              const float* __restrict__ noise,
                                              float* __restrict__ L0,
                                              float* __restrict__ c) {
    int idx = blockIdx.x * blockDim.x + threadIdx.x;
    int stride = gridDim.x * blockDim.x;
    const float4* l4 = (const float4*)logits;
    const float4* n4 = (const float4*)noise;
    float4* o4 = (float4*)L0;
    for (int p = idx; p < DIM * DIM / 4; p += stride) {
        float4 l = l4[p];
        float4 u = n4[p];
        float4 o;
        o.x = l.x - __logf(-__logf(u.x + EPSF) + EPSF);
        o.y = l.y - __logf(-__logf(u.y + EPSF) + EPSF);
        o.z = l.z - __logf(-__logf(u.z + EPSF) + EPSF);
        o.w = l.w - __logf(-__logf(u.w + EPSF) + EPSF);
        o4[p] = o;
    }
    if (idx < DIM) c[idx] = 0.0f;
}

__global__ __launch_bounds__(256) void row_lse(const float* __restrict__ L0,
                                               const float* __restrict__ c,
                                               float* __restrict__ r) {
    __shared__ float red[8];
    const int row = blockIdx.x;
    const int t = threadIdx.x;
    const float4* a4 = (const float4*)(L0 + (size_t)row * DIM);
    const float4* c4 = (const float4*)c;
    float v[16];
    float m = -INFINITY;
#pragma unroll
    for (int k = 0; k < 4; ++k) {
        float4 a  = a4[t + k * 256];
        float4 cc = c4[t + k * 256];
        v[4 * k + 0] = a.x - cc.x;
        v[4 * k + 1] = a.y - cc.y;
        v[4 * k + 2] = a.z - cc.z;
        v[4 * k + 3] = a.w - cc.w;
        m = fmaxf(m, fmaxf(fmaxf(v[4 * k], v[4 * k + 1]), fmaxf(v[4 * k + 2], v[4 * k + 3])));
    }
    m = waveMaxF(m);
    const int lane = t & 63, wid = t >> 6;
    if (lane == 0) red[wid] = m;
    __syncthreads();
    const float bm = fmaxf(fmaxf(red[0], red[1]), fmaxf(red[2], red[3]));
    float s = 0.0f;
#pragma unroll
    for (int q = 0; q < 16; ++q) s += __expf(v[q] - bm);
    s = waveSumF(s);
    if (lane == 0) red[4 + wid] = s;
    __syncthreads();
    if (t == 0) r[row] = bm + __logf(red[4] + red[5] + red[6] + red[7]);
}

__global__ __launch_bounds__(1024) void col_partial(const float* __restrict__ L0,
                                                    const float* __restrict__ r,
                                                    float2* __restrict__ part) {
    __shared__ float sr[256];
    __shared__ float smm[1024];
    __shared__ float sms[1024];
    const int g = blockIdx.x, h = blockIdx.y;
    const int tc = threadIdx.x & 255;
    const int ln = threadIdx.x >> 8;
    if (threadIdx.x < 256) sr[threadIdx.x] = r[h * 256 + threadIdx.x];
    __syncthreads();
    const int j = g * 256 + tc;
    float m = -INFINITY, s = 0.0f;
#pragma unroll 4
    for (int k = 0; k < 64; ++k) {
        int ii = k * 4 + ln;
        float v = L0[(size_t)(h * 256 + ii) * DIM + j] - sr[ii];
        float nm = fmaxf(m, v);
        s = s * __expf(m - nm) + __expf(v - nm);
        m = nm;
    }
    smm[threadIdx.x] = m;
    sms[threadIdx.x] = s;
    __syncthreads();
    if (threadIdx.x < 256) {
        float m0 = smm[tc], m1 = smm[tc + 256], m2 = smm[tc + 512], m3 = smm[tc + 768];
        float M = fmaxf(fmaxf(m0, m1), fmaxf(m2, m3));
        float S = sms[tc] * __expf(m0 - M) + sms[tc + 256] * __expf(m1 - M) +
                  sms[tc + 512] * __expf(m2 - M) + sms[tc + 768] * __expf(m3 - M);
        part[h * DIM + j] = make_float2(M, S);
    }
}

__global__ __launch_bounds__(256) void col_combine(const float2* __restrict__ part,
                                                   float* __restrict__ c) {
    int j = blockIdx.x * 256 + threadIdx.x;
    float pm[NRG], ps[NRG];
    float M = -INFINITY;
#pragma unroll
    for (int h = 0; h < NRG; ++h) {
        float2 p = part[h * DIM + j];
        pm[h] = p.x; ps[h] = p.y;
        M = fmaxf(M, p.x);
    }
    float S = 0.0f;
#pragma unroll
    for (int h = 0; h < NRG; ++h) S += ps[h] * __expf(pm[h] - M);
    c[j] = M + __logf(S);
}

__global__ __launch_bounds__(256) void final_exp(float* __restrict__ L0,
                                                 const float* __restrict__ r,
                                                 const float* __restrict__ c) {
    const float4* c4 = (const float4*)c;
    float4* a4 = (float4*)L0;
    int idx = blockIdx.x * blockDim.x + threadIdx.x;
    int stride = gridDim.x * blockDim.x;
    for (int p = idx; p < DIM * DIM / 4; p += stride) {
        int i  = p >> 10;
        int j4 = p & 1023;
        float4 a = a4[p];
        float rrv = r[i];
        float4 ccv = c4[j4];
        a.x = __expf(a.x - rrv - ccv.x);
        a.y = __expf(a.y - rrv - ccv.y);
        a.z = __expf(a.z - rrv - ccv.z);
        a.w = __expf(a.w - rrv - ccv.w);
        a4[p] = a;
    }
}

// ====================================== launch ===================================
extern "C" void kernel_launch(void* const* d_in, const int* in_sizes, int n_in,
                              void* d_out, int out_size, void* d_ws, size_t ws_size,
                              hipStream_t stream) {
    const float* logits = (const float*)d_in[0];
    const float* noise  = (const float*)d_in[1];
    float* out = (float*)d_out;

    bool tried_flow = false;
    if (ws_size >= 33792) {
        u64* cgt        = (u64*)d_ws;                         // 32 KiB tagged w
        unsigned* slots = (unsigned*)((char*)d_ws + 32768);   //  1 KiB barrier slots
        float* part     = (float*)d_out;                      // 4 MiB f32 partials
        zero_scratch<<<16, 256, 0, stream>>>(cgt, slots);
        void* args[] = { (void*)&logits, (void*)&noise, (void*)&out,
                         (void*)&cgt, (void*)&slots, (void*)&part };
        hipError_t err = hipLaunchCooperativeKernel((const void*)sinkhorn_flow,
                                                    dim3(NB), dim3(NT), args, 0, stream);
        tried_flow = (err == hipSuccess);
    }
    if (!tried_flow) {
        // fallback: round-1 multi-kernel pipeline (known-good)
        float* ws = (float*)d_ws;
        float*  r    = ws;
        float*  cf   = ws + DIM;
        float2* part = (float2*)(ws + 2 * DIM);
        init_k<<<4096, 256, 0, stream>>>(logits, noise, out, cf);
        for (int t = 0; t < NITER; ++t) {
            row_lse<<<DIM, 256, 0, stream>>>(out, cf, r);
            col_partial<<<dim3(16, 16), 1024, 0, stream>>>(out, r, part);
            col_combine<<<16, 256, 0, stream>>>(part, cf);
        }
        final_exp<<<4096, 256, 0, stream>>>(out, r, cf);
    }
}